// Round 3
// baseline (18258.200 us; speedup 1.0000x reference)
//
#include <hip/hip_runtime.h>
#include <stdint.h>

// BiLSTM fused: B=64, T=1024, D=256, H=256/dir, O=64. In fp32, out fp32.
// R11 @14.1ms (7.07ms/layer): wave-flags, atomic-store data, vmcnt(0) drain.
// R12 @16.3ms: sentinel data-poll REGRESSED (+1.8us/step) -> atomic loads
// never coalesce; 16 scattered 8B polls/lane/round is a packet storm.
// R13 theory: the dominant term all along is the DATA PUBLISH atomic storm:
// 64 per-lane 8B agent-atomic stores per wave (atomics don't coalesce) =
// ~8192 packets/step at the coherent point; the producer drain waits the
// tail of its own 64 serialized acks. Fix the transport mode:
//   - producers write their 512B slot with PLAIN stores (coalesce to 4
//     lines, write-through L1 -> L2),
//   - one __builtin_amdgcn_fence(RELEASE, "agent") = s_waitcnt vmcnt(0) +
//     buffer_wbl2 (flush ~4 full dirty lines to L3, not 64 atomic acks),
//   - one relaxed agent flag store by lane 0 (R11 flag layout, proven).
//   - consumer: R11 relaxed flag poll, predicated to 16 lanes (16 packets
//     per round, was 64), then PLAIN coalesced loads. Freshness argument
//     proven in R10/R11: each (t,w,g) slot is written once and no cache can
//     hold a pre-write copy (nobody reads before its flag); kernel-boundary
//     coherence covers cross-kernel readers.
//   - exchange layout [t][4 w][16 g][16 b][16 j] bf16: producer slot is
//     wave-exclusive (full-line ownership for wbl2), consumer wave's step
//     working set is 8KB CONTIGUOUS (fully coalesced short8 loads).
//   - layer-0 Wih back to VGPR-resident (R12's streaming was a regression).
//
// Structure: 32 WGs per layer (2 dirs x 16 hidden-slices g); WG g owns hidden
// cols j in [16g,16g+16) == gate rows {j,256+j,512+j,768+j}.
//   acc[gate] = bias + Wih @ x[t]^T + Whh @ h[t-1]^T      (D[j][b], fp32 acc)
//
// Memory plan: d_ws = h0 exch [2][1024][4][16][16][16] bf16 (64MB).
//   x buf (d_in[0], fp32, 64MB, dead after layer-0) -> h1 bf16 (exact fit).
//   d_out (16MB): [0,2MB) flags u32[2 layer][2 dir][1024 t][4 w][32 pad]
//   | [2MB,+2MB) wb1 = Wih_l1 bf16. FC head runs last, overwrites d_out.

typedef __attribute__((ext_vector_type(8))) short short8;   // 8 x bf16
typedef __attribute__((ext_vector_type(4))) float floatx4;  // MFMA acc

#define MFMA_BF16(A, B, C) __builtin_amdgcn_mfma_f32_16x16x32_bf16(A, B, C, 0, 0, 0)

__device__ __forceinline__ unsigned short f2bf(float f) {
  unsigned u = __float_as_uint(f);
  u += 0x7FFFu + ((u >> 16) & 1u);  // RNE
  return (unsigned short)(u >> 16);
}
__device__ __forceinline__ short8 load_cvt8(const float* p) {
  short8 r;
#pragma unroll
  for (int i = 0; i < 8; ++i) r[i] = (short)f2bf(p[i]);
  return r;
}
// NaN-killing clamps; inert for legit values (|gate preact| <~ 5, fc <~ 0.6).
__device__ __forceinline__ float clamp_gate(float x) { return fminf(30.f, fmaxf(-30.f, x)); }
__device__ __forceinline__ float clamp_fc(float x) { return fminf(4.f, fmaxf(-30.f, x)); }
__device__ __forceinline__ float sigm(float x) { return 1.0f / (1.0f + __expf(-x)); }
__device__ __forceinline__ float tanh_fast(float x) { return 1.0f - 2.0f / (1.0f + __expf(2.0f * x)); }

// ---------------------------------------------------------------------------
// fp32 -> bf16 conversion, grid-strided.
// ---------------------------------------------------------------------------
__global__ __launch_bounds__(256) void cvt_kernel(
    const float* __restrict__ s0, unsigned short* __restrict__ d0, int n0,
    const float* __restrict__ s1, unsigned short* __restrict__ d1, int n1) {
  const int stride = gridDim.x * 256;
  for (int j = blockIdx.x * 256 + threadIdx.x; j < n0; j += stride) d0[j] = f2bf(s0[j]);
  for (int j = blockIdx.x * 256 + threadIdx.x; j < n1; j += stride) d1[j] = f2bf(s1[j]);
}

// ---------------------------------------------------------------------------
// One bidirectional LSTM layer, fused input GEMM + recurrence.
// LAYER=0: input = x fp32 [B][T][256] (per-step cvt), Wih fp32 -> VGPRs once.
// LAYER=1: input = h0 exch layout bf16 (K=512 concat), Wih = wb1 bf16 stream.
// Exchange layout per dir: [1024 t][4 w][16 g][16 b_l][16 j_l] bf16.
// ---------------------------------------------------------------------------
template <int LAYER>
__global__ __launch_bounds__(256, 1) void lstm_layer_kernel(
    const float* __restrict__ xf32,          // LAYER 0 input
    const unsigned short* __restrict__ xbf,  // LAYER 1 input (h0, exch layout)
    const float* __restrict__ WihF32, const float* __restrict__ WihB32,  // L0
    const unsigned short* __restrict__ wb1,  // L1 Wih bf16 [2][1024][512]
    const float* __restrict__ WhhF, const float* __restrict__ WhhB,
    const float* __restrict__ bF, const float* __restrict__ bB,
    unsigned short* __restrict__ hout,       // exch layout [2][...]
    unsigned int* __restrict__ flags) {      // this layer's [2][1024][4][32]
  constexpr int NKS = LAYER ? 16 : 8;
  constexpr size_t DIRSZ = (size_t)1024 * 16384;  // shorts per dir

  const int bx = blockIdx.x;
  const int dir = bx >> 4;
  const int g = bx & 15;
  const int tid = threadIdx.x;
  const int w = tid >> 6, l = tid & 63, l15 = l & 15, q = l >> 4;

  const float* Whh = dir ? WhhB : WhhF;
  const float* bias = dir ? bB : bF;

  // Whh A-fragments: cvt fp32 -> bf16 once (lane l15 -> j-row, q -> k-quad).
  short8 whh[4][8];
#pragma unroll
  for (int gi = 0; gi < 4; ++gi) {
    const float* wr = Whh + (size_t)(gi * 256 + g * 16 + l15) * 256;
#pragma unroll
    for (int ks = 0; ks < 8; ++ks) whh[gi][ks] = load_cvt8(wr + ks * 32 + q * 8);
  }

  // Layer 0 only: Wih fragments resident in VGPRs.
  short8 wih0[4][LAYER ? 1 : 8];
  if (LAYER == 0) {
    const float* Wih = dir ? WihB32 : WihF32;
#pragma unroll
    for (int gi = 0; gi < 4; ++gi) {
      const float* wr = Wih + (size_t)(gi * 256 + g * 16 + l15) * 256;
#pragma unroll
      for (int ks = 0; ks < (LAYER ? 1 : 8); ++ks)
        wih0[gi][ks] = load_cvt8(wr + ks * 32 + q * 8);
    }
  }
  const unsigned short* wb1d = wb1 + (size_t)dir * 1024 * 512;

  // Bias (fp32) for this lane's 16 outputs (gi, r) at j = g*16 + q*4 + r.
  float bvp[16];
#pragma unroll
  for (int gi = 0; gi < 4; ++gi)
#pragma unroll
    for (int r = 0; r < 4; ++r) bvp[gi * 4 + r] = bias[gi * 256 + g * 16 + q * 4 + r];

  const int b = w * 16 + l15;  // batch index this lane feeds (B-fragment)
  unsigned short* hd = hout + (size_t)dir * DIRSZ;
  // Per-dir flag block: [1024 t][4 w][32 pad] u32; slot (t,w) is one 128B line.
  unsigned int* fl = flags + (size_t)dir * 1024 * 4 * 32;

  float c[4] = {0.f, 0.f, 0.f, 0.f};

  for (int it = 0; it < 1024; ++it) {
    const int t = dir ? (1023 - it) : it;
    const int tp = dir ? (t + 1) : (t - 1);

    floatx4 acc[4];
#pragma unroll
    for (int gi = 0; gi < 4; ++gi)
#pragma unroll
      for (int r = 0; r < 4; ++r) acc[gi][r] = bvp[gi * 4 + r];

    // ---- x-part (independent of h[t-1]; overlaps peers' publish) ----
#pragma unroll
    for (int ks = 0; ks < NKS; ++ks) {
      short8 xf;
      if (LAYER == 0) {
        xf = load_cvt8(xf32 + (((size_t)b << 10) + t) * 256 + ks * 32 + q * 8);
      } else {
        const int k = ks * 32 + q * 8;
        const int gp = (k & 255) >> 4;  // = (ks&7)*2 + (q>>1)
        const size_t off = (size_t)(k >> 8) * DIRSZ +
                           (((size_t)t * 4 + w) * 16 + gp) * 256 + l15 * 16 +
                           (k & 15);
        xf = *(const short8*)(xbf + off);
      }
#pragma unroll
      for (int gi = 0; gi < 4; ++gi) {
        short8 wfrag;
        if (LAYER == 0)
          wfrag = wih0[gi][LAYER ? 0 : ks];
        else
          wfrag = *(const short8*)(wb1d + (size_t)(gi * 256 + g * 16 + l15) * 512 +
                                   ks * 32 + q * 8);
        acc[gi] = MFMA_BF16(wfrag, xf, acc[gi]);
      }
    }

    // ---- recurrent part: 16-lane flag poll, then plain coalesced loads ----
    if (it > 0) {
      const unsigned int* fp = fl + (((unsigned)tp * 4 + w) << 5);
      for (;;) {
        unsigned v = (l < 16)
            ? __hip_atomic_load(fp + l, __ATOMIC_RELAXED, __HIP_MEMORY_SCOPE_AGENT)
            : 1u;
        if (__all(v != 0)) break;
        __builtin_amdgcn_s_sleep(1);
      }

      // Wave's step working set: 16 slots x 512B = 8KB contiguous.
      const unsigned short* hbase = hd + ((size_t)tp * 4 + w) * (16 * 256);
#pragma unroll
      for (int ks = 0; ks < 8; ++ks) {
        const int gp = ks * 2 + (q >> 1);
        short8 hf = *(const short8*)(hbase + (size_t)gp * 256 + l15 * 16 + (q & 1) * 8);
#pragma unroll
        for (int gi = 0; gi < 4; ++gi) acc[gi] = MFMA_BF16(whh[gi][ks], hf, acc[gi]);
      }
    }

    // ---- gates (i,f,g,o all in this lane) ----
    unsigned long long hv = 0ull;
#pragma unroll
    for (int r = 0; r < 4; ++r) {
      const float si = sigm(clamp_gate(acc[0][r]));
      const float sf = sigm(clamp_gate(acc[1][r]));
      const float tg = tanh_fast(clamp_gate(acc[2][r]));
      const float so = sigm(clamp_gate(acc[3][r]));
      const float cn = sf * c[r] + si * tg;
      c[r] = cn;
      const unsigned short hb16 = f2bf(so * tanh_fast(cn));
      hv |= ((unsigned long long)hb16) << (16 * r);
    }

    // ---- publish: PLAIN coalesced store -> release fence -> flag ----
    // Slot (t,w,g) is wave-exclusive (4 full 128B lines). Plain store
    // coalesces; the agent-release fence (waitcnt + buffer_wbl2) pushes the
    // dirty lines to the coherent point before the flag is set.
    *(unsigned long long*)(hd + (((size_t)t * 4 + w) * 16 + g) * 256 +
                           l15 * 16 + q * 4) = hv;
    __builtin_amdgcn_fence(__ATOMIC_RELEASE, "agent");
    if (l == 0)
      __hip_atomic_store(fl + (((unsigned)t * 4 + w) << 5) + g, 1u,
                         __ATOMIC_RELAXED, __HIP_MEMORY_SCOPE_AGENT);
  }
}

// ---------------------------------------------------------------------------
// FC head: out[b][t][o] = exp(h1concat[t][b][:] @ fc_W[o][:]^T + fc_b[o])
// h1 is in exch layout. fc_W fp32 -> bf16 into LDS once per block. Grid 1024
// x 256thr; block covers 64 rows (m = b*1024+t). OUTPUT FP32.
// ---------------------------------------------------------------------------
__global__ __launch_bounds__(256) void fc_head_kernel(
    const unsigned short* __restrict__ h1,  // exch layout [2][...] bf16
    const float* __restrict__ fcW,          // [64][512] fp32
    const float* __restrict__ fcb,          // [64] fp32
    float* __restrict__ out) {              // [B][T][64] fp32
  constexpr size_t DIRSZ = (size_t)1024 * 16384;
  __shared__ unsigned short sW[64 * 512];
  const int tid = threadIdx.x;
  for (int i = tid; i < 64 * 512; i += 256) sW[i] = f2bf(fcW[i]);
  __syncthreads();

  const int w = tid >> 6, l = tid & 63, l15 = l & 15, q = l >> 4;
  const int m0 = blockIdx.x * 64 + w * 16;

  const int mA = m0 + l15;
  const int bA = mA >> 10, tA = mA & 1023;
  // Lane's A-row base within a dir: [tA][w'=bA>>4][g'][b_l=bA&15][j_l].
  const size_t arow = ((size_t)tA * 4 + (bA >> 4)) * (16 * 256) +
                      (size_t)(bA & 15) * 16 + (q & 1) * 8;

  floatx4 acc[4];
#pragma unroll
  for (int nt = 0; nt < 4; ++nt) acc[nt] = (floatx4){0.f, 0.f, 0.f, 0.f};

#pragma unroll
  for (int dh = 0; dh < 2; ++dh) {
    const unsigned short* ad = h1 + (size_t)dh * DIRSZ;
#pragma unroll
    for (int ks = 0; ks < 8; ++ks) {
      const int gp = ks * 2 + (q >> 1);
      short8 af = *(const short8*)(ad + arow + (size_t)gp * 256);
#pragma unroll
      for (int nt = 0; nt < 4; ++nt) {
        short8 bf = *(const short8*)(sW + (nt * 16 + l15) * 512 + dh * 256 +
                                     ks * 32 + q * 8);
        acc[nt] = MFMA_BF16(af, bf, acc[nt]);
      }
    }
  }

#pragma unroll
  for (int nt = 0; nt < 4; ++nt) {
    const float bv = fcb[nt * 16 + l15];
#pragma unroll
    for (int r = 0; r < 4; ++r) {
      const int m = m0 + q * 4 + r;
      out[(size_t)m * 64 + nt * 16 + l15] = __expf(clamp_fc(acc[nt][r] + bv));
    }
  }
}

// ---------------------------------------------------------------------------
__global__ void diag_kernel(float* out, int n, float code) {
  int i = blockIdx.x * 256 + threadIdx.x;
  if (i < n) out[i] = (i == 0) ? code : 1.0f;
}

// ---------------------------------------------------------------------------

extern "C" void kernel_launch(void* const* d_in, const int* in_sizes, int n_in,
                              void* d_out, int out_size, void* d_ws, size_t ws_size,
                              hipStream_t stream) {
  const float* x       = (const float*)d_in[0];
  const float* Wih_l0f = (const float*)d_in[1];
  const float* Whh_l0f = (const float*)d_in[2];
  const float* b_l0f   = (const float*)d_in[3];
  const float* Wih_l0b = (const float*)d_in[4];
  const float* Whh_l0b = (const float*)d_in[5];
  const float* b_l0b   = (const float*)d_in[6];
  const float* Wih_l1f = (const float*)d_in[7];
  const float* Whh_l1f = (const float*)d_in[8];
  const float* b_l1f   = (const float*)d_in[9];
  const float* Wih_l1b = (const float*)d_in[10];
  const float* Whh_l1b = (const float*)d_in[11];
  const float* b_l1b   = (const float*)d_in[12];
  const float* fc_W    = (const float*)d_in[13];
  const float* fc_b    = (const float*)d_in[14];
  float* out = (float*)d_out;

  const size_t H_BYTES = (size_t)2 * 1024 * 64 * 256 * 2;  // 64MB

  if (ws_size < H_BYTES) {
    diag_kernel<<<dim3((out_size + 255) / 256), dim3(256), 0, stream>>>(
        out, out_size, 200.0f + (float)(ws_size >> 20));
    return;
  }

  unsigned short* h0 = (unsigned short*)d_ws;     // exch layout, 64MB
  unsigned short* h1 = (unsigned short*)d_in[0];  // x buf (fp32, 64MB): dead
                                                  // after layer-0 -> h1 bf16
  // d_out: [0,2MB) flags u32[2 layer][2 dir][1024][4][32] | [2MB,+2MB) wb1.
  unsigned int* flags = (unsigned int*)d_out;
  unsigned short* wb1 = (unsigned short*)((uint8_t*)d_out + (2u << 20));
  const size_t FLAGS_PER_LAYER = (size_t)2 * 1024 * 4 * 32;  // u32 words

  hipMemsetAsync(flags, 0, 2u << 20, stream);

  // Wih_l1{f,b} fp32 -> bf16 into d_out's dead prefix.
  cvt_kernel<<<dim3(512), dim3(256), 0, stream>>>(
      Wih_l1f, wb1, 1024 * 512, Wih_l1b, wb1 + (size_t)1024 * 512, 1024 * 512);

  lstm_layer_kernel<0><<<dim3(32), dim3(256), 0, stream>>>(
      x, nullptr, Wih_l0f, Wih_l0b, nullptr, Whh_l0f, Whh_l0b, b_l0f, b_l0b,
      h0, flags);
  lstm_layer_kernel<1><<<dim3(32), dim3(256), 0, stream>>>(
      nullptr, h0, nullptr, nullptr, wb1, Whh_l1f, Whh_l1b, b_l1f, b_l1b,
      h1, flags + FLAGS_PER_LAYER);
  fc_head_kernel<<<dim3(1024), dim3(256), 0, stream>>>(h1, fc_W, fc_b, out);
}

// Round 4
// 14249.187 us; speedup vs baseline: 1.2814x; 1.2814x over previous
//
#include <hip/hip_runtime.h>
#include <stdint.h>

// BiLSTM fused: B=64, T=1024, D=256, H=256/dir, O=64. In fp32, out fp32.
// R11 @14.1ms (7.07ms/layer = 6.9us/step) is the best protocol; R12/R13
// transport variants both regressed. Post-mortem: relaxed agent atomics are
// plain loads/stores with sc bits (they coalesce) -> no packet storm ever
// existed; L0==L1 duration -> BW/compute irrelevant; all variants floor at
// ~14.5k cy/step @2.4GHz nominal vs a ~3k cy worst-case latency chain.
// R14 theory: the x4 multiplier is DVFS. 32 WGs / 2% VALUBusy = near-idle
// chip -> SCLK at floor (~550MHz); 6.9us/step ~= 3.8k cy there, matching the
// chain. Evidence: variants that ADDED idleness (R12 sleepy polls, R13
// fences) ran SLOWER. Fix: keep R11's exchange byte-identical, add HEATER
// workgroups (grid 256; bx>=32 spin dense independent FMA, no memory
// traffic) that exit when the 32 real WGs bump a done-counter; drop s_sleep
// from the real poll (stay hot, detect sooner -- spinning steals nothing at
// ~1 real wave/CU).
//
// Structure (real WGs, unchanged from R11): 32 WGs per layer (2 dirs x 16
// hidden-slices g); WG g owns hidden cols j in [16g,16g+16) == gate rows
// {j,256+j,512+j,768+j}; Whh (and layer-0 Wih) slices live in VGPRs.
//   acc[gate] = bias + Wih @ x[t]^T + Whh @ h[t-1]^T      (D[j][b], fp32 acc)
// Exchange: producers publish h with write-through agent-scope 8B stores,
// drain own wave (vmcnt(0)), lane0 sets per-(wave,g) flag; consumers poll
// their 16 flag dwords coalesced (lanes 16..63 duplicate), then plain-load
// hist[t-1] (each gated line written once; nobody reads before its flag).
//
// Memory plan: d_ws = h0 [2][T][B][256] bf16 (64MB).
//   x buf (d_in[0], fp32, 64MB, dead after layer-0) -> h1 bf16 (exact fit).
//   d_out (16MB): [0,~2MB) flags: per layer {u32[2 dir][1024 t][4 w][32 pad]
//     + 32-word done line}; | [4MB,+2MB) wb1 = Wih_l1 bf16.
//   FC head runs last, overwrites all of d_out.

typedef __attribute__((ext_vector_type(8))) short short8;   // 8 x bf16
typedef __attribute__((ext_vector_type(4))) float floatx4;  // MFMA acc

#define MFMA_BF16(A, B, C) __builtin_amdgcn_mfma_f32_16x16x32_bf16(A, B, C, 0, 0, 0)

__device__ __forceinline__ unsigned short f2bf(float f) {
  unsigned u = __float_as_uint(f);
  u += 0x7FFFu + ((u >> 16) & 1u);  // RNE
  return (unsigned short)(u >> 16);
}
__device__ __forceinline__ short8 load_cvt8(const float* p) {
  short8 r;
#pragma unroll
  for (int i = 0; i < 8; ++i) r[i] = (short)f2bf(p[i]);
  return r;
}
// NaN-killing clamps; inert for legit values (|gate preact| <~ 5, fc <~ 0.6).
__device__ __forceinline__ float clamp_gate(float x) { return fminf(30.f, fmaxf(-30.f, x)); }
__device__ __forceinline__ float clamp_fc(float x) { return fminf(4.f, fmaxf(-30.f, x)); }
__device__ __forceinline__ float sigm(float x) { return 1.0f / (1.0f + __expf(-x)); }
__device__ __forceinline__ float tanh_fast(float x) { return 1.0f - 2.0f / (1.0f + __expf(2.0f * x)); }

// ---------------------------------------------------------------------------
// fp32 -> bf16 conversion (two regions), grid-strided.
// ---------------------------------------------------------------------------
__global__ __launch_bounds__(256) void cvt_kernel(
    const float* __restrict__ s0, unsigned short* __restrict__ d0, int n0,
    const float* __restrict__ s1, unsigned short* __restrict__ d1, int n1) {
  const int stride = gridDim.x * 256;
  for (int j = blockIdx.x * 256 + threadIdx.x; j < n0; j += stride) d0[j] = f2bf(s0[j]);
  for (int j = blockIdx.x * 256 + threadIdx.x; j < n1; j += stride) d1[j] = f2bf(s1[j]);
}

// ---------------------------------------------------------------------------
// One bidirectional LSTM layer, fused input GEMM + recurrence.
// LAYER=0: input = x fp32 [B][T][256] (per-step cvt), Wih fp32 -> VGPRs once.
// LAYER=1: input = h0 bf16 [2][T][B][256] concat (K=512), Wih = wb1 bf16
//          streamed from cache each step.
// Grid = 256 WGs: bx<32 do the LSTM (2 dirs x 16 g); bx>=32 are HEATERS
// keeping SCLK boosted (dense VALU FMA, no memory traffic except a rare
// done-poll), exiting when all 32 real WGs have bumped the done counter.
// ---------------------------------------------------------------------------
template <int LAYER>
__global__ __launch_bounds__(256, 1) void lstm_layer_kernel(
    const float* __restrict__ xf32,          // LAYER 0 input
    const unsigned short* __restrict__ xbf,  // LAYER 1 input (h0)
    const float* __restrict__ WihF32, const float* __restrict__ WihB32,  // L0
    const unsigned short* __restrict__ wb1,  // L1 Wih bf16 [2][1024][512]
    const float* __restrict__ WhhF, const float* __restrict__ WhhB,
    const float* __restrict__ bF, const float* __restrict__ bB,
    unsigned short* __restrict__ hist,       // [2][T][B][256] bf16
    unsigned int* __restrict__ flags) {      // layer base: [2][1024][4][32]+done
  constexpr int NKS = LAYER ? 16 : 8;

  const int bx = blockIdx.x;
  const int tid = threadIdx.x;
  const int w = tid >> 6, l = tid & 63, l15 = l & 15, q = l >> 4;

  unsigned int* done = flags + 2 * 1024 * 4 * 32;  // 1 line past flag block

  // ---------------- HEATER ----------------
  if (bx >= 32) {
    float s0 = 0.125f + 0.001f * (float)tid, s1 = s0 + 0.37f, s2 = s0 + 0.71f,
          s3 = s0 + 1.13f;
    const float a = 1.0000001f, c0 = 1e-9f;
    for (int blk = 0; blk < 24000; ++blk) {
#pragma unroll
      for (int i = 0; i < 128; ++i) {
        s0 = __builtin_fmaf(s0, a, c0);
        s1 = __builtin_fmaf(s1, a, c0);
        s2 = __builtin_fmaf(s2, a, c0);
        s3 = __builtin_fmaf(s3, a, c0);
      }
      if (((blk + bx) & 31) == 0 &&
          __hip_atomic_load(done, __ATOMIC_RELAXED, __HIP_MEMORY_SCOPE_AGENT) >= 32u)
        break;
    }
    // Unreachable (s0..s3 stay positive & finite); keeps the FMA chain live.
    if (s0 + s1 + s2 + s3 == -1.25e36f && l == 63) done[16] = 1u;
    return;
  }

  // ---------------- REAL LSTM WG (identical to R11) ----------------
  const int dir = bx >> 4;
  const int g = bx & 15;

  const float* Whh = dir ? WhhB : WhhF;
  const float* bias = dir ? bB : bF;

  // Whh A-fragments: cvt fp32 -> bf16 once (lane l15 -> j-row, q -> k-quad).
  short8 whh[4][8];
#pragma unroll
  for (int gi = 0; gi < 4; ++gi) {
    const float* wr = Whh + (size_t)(gi * 256 + g * 16 + l15) * 256;
#pragma unroll
    for (int ks = 0; ks < 8; ++ks) whh[gi][ks] = load_cvt8(wr + ks * 32 + q * 8);
  }

  // Layer 0 only: Wih fragments resident in VGPRs.
  short8 wih0[4][LAYER ? 1 : 8];
  if (LAYER == 0) {
    const float* Wih = dir ? WihB32 : WihF32;
#pragma unroll
    for (int gi = 0; gi < 4; ++gi) {
      const float* wr = Wih + (size_t)(gi * 256 + g * 16 + l15) * 256;
#pragma unroll
      for (int ks = 0; ks < (LAYER ? 1 : 8); ++ks)
        wih0[gi][ks] = load_cvt8(wr + ks * 32 + q * 8);
    }
  }
  const unsigned short* wb1d = wb1 + (size_t)dir * 1024 * 512;

  // Bias (fp32) for this lane's 16 outputs (gi, r) at j = g*16 + q*4 + r.
  float bvp[16];
#pragma unroll
  for (int gi = 0; gi < 4; ++gi)
#pragma unroll
    for (int r = 0; r < 4; ++r) bvp[gi * 4 + r] = bias[gi * 256 + g * 16 + q * 4 + r];

  const int b = w * 16 + l15;     // batch index this lane feeds (B-fragment)
  const int jq = g * 16 + q * 4;  // j base of this lane's 4 packed h outputs
  unsigned short* hd = hist + (size_t)dir * 1024 * 64 * 256;
  // Per-dir flag block: [1024 t][4 w][32 pad] u32; slot (t,w) is one 128B line.
  unsigned int* fl = flags + (size_t)dir * 1024 * 4 * 32;

  float c[4] = {0.f, 0.f, 0.f, 0.f};

  for (int it = 0; it < 1024; ++it) {
    const int t = dir ? (1023 - it) : it;
    const int tp = dir ? (t + 1) : (t - 1);

    floatx4 acc[4];
#pragma unroll
    for (int gi = 0; gi < 4; ++gi)
#pragma unroll
      for (int r = 0; r < 4; ++r) acc[gi][r] = bvp[gi * 4 + r];

    // ---- x-part (independent of h[t-1]; overlaps peers' publish) ----
#pragma unroll
    for (int ks = 0; ks < NKS; ++ks) {
      const int k = ks * 32 + q * 8;
      short8 xf;
      if (LAYER == 0) {
        xf = load_cvt8(xf32 + (((size_t)b << 10) + t) * 256 + k);
      } else {
        const size_t off = ((size_t)t * 64 + b) * 256 +
                           (size_t)(k >> 8) * (1024u * 64u * 256u) + (size_t)(k & 255);
        xf = *(const short8*)(xbf + off);
      }
#pragma unroll
      for (int gi = 0; gi < 4; ++gi) {
        short8 wfrag;
        if (LAYER == 0)
          wfrag = wih0[gi][LAYER ? 0 : ks];
        else
          wfrag = *(const short8*)(wb1d + (size_t)(gi * 256 + g * 16 + l15) * 512 +
                                   ks * 32 + q * 8);
        acc[gi] = MFMA_BF16(wfrag, xf, acc[gi]);
      }
    }

    // ---- recurrent part: 16-lane coalesced flag poll (hot spin), then
    //      plain cached vector loads of hist[t-1] ----
    if (it > 0) {
      const unsigned int* fp = fl + (((unsigned)tp * 4 + w) << 5);
      for (;;) {
        unsigned v = (l < 16)
            ? __hip_atomic_load(fp + l, __ATOMIC_RELAXED, __HIP_MEMORY_SCOPE_AGENT)
            : 1u;
        if (__all(v != 0)) break;
      }

      const unsigned short* hp = hd + (size_t)tp * 16384 + (size_t)b * 256;
#pragma unroll
      for (int ks = 0; ks < 8; ++ks) {
        short8 hf = *(const short8*)(hp + ks * 32 + q * 8);
#pragma unroll
        for (int gi = 0; gi < 4; ++gi) acc[gi] = MFMA_BF16(whh[gi][ks], hf, acc[gi]);
      }
    }

    // ---- gates (i,f,g,o all in this lane) ----
    unsigned long long hv = 0ull;
#pragma unroll
    for (int r = 0; r < 4; ++r) {
      const float si = sigm(clamp_gate(acc[0][r]));
      const float sf = sigm(clamp_gate(acc[1][r]));
      const float tg = tanh_fast(clamp_gate(acc[2][r]));
      const float so = sigm(clamp_gate(acc[3][r]));
      const float cn = sf * c[r] + si * tg;
      c[r] = cn;
      const unsigned short hb16 = f2bf(so * tanh_fast(cn));
      hv |= ((unsigned long long)hb16) << (16 * r);
    }

    // ---- publish h: write-through store -> per-wave drain -> flag ----
    __hip_atomic_store(
        (unsigned long long*)(hd + (size_t)t * 16384 + (size_t)b * 256 + jq),
        hv, __ATOMIC_RELAXED, __HIP_MEMORY_SCOPE_AGENT);
    asm volatile("s_waitcnt vmcnt(0)" ::: "memory");  // this wave's stores acked
    if (l == 0)
      __hip_atomic_store(fl + (((unsigned)t * 4 + w) << 5) + g, 1u,
                         __ATOMIC_RELAXED, __HIP_MEMORY_SCOPE_AGENT);
  }

  // Signal heaters: this WG is done.
  if (tid == 0)
    __hip_atomic_fetch_add(done, 1u, __ATOMIC_RELAXED, __HIP_MEMORY_SCOPE_AGENT);
}

// ---------------------------------------------------------------------------
// FC head: out[b][t][o] = exp(h1concat[t][b][:] @ fc_W[o][:]^T + fc_b[o])
// fc_W fp32 -> bf16 into LDS once per block. Grid 1024 x 256thr; block covers
// 64 rows (m = b*1024+t). OUTPUT FP32. Runs last; overwrites all of d_out.
// ---------------------------------------------------------------------------
__global__ __launch_bounds__(256) void fc_head_kernel(
    const unsigned short* __restrict__ h1,  // [2][T][B][256] bf16 (x buffer)
    const float* __restrict__ fcW,          // [64][512] fp32
    const float* __restrict__ fcb,          // [64] fp32
    float* __restrict__ out) {              // [B][T][64] fp32
  __shared__ unsigned short sW[64 * 512];
  const int tid = threadIdx.x;
  for (int i = tid; i < 64 * 512; i += 256) sW[i] = f2bf(fcW[i]);
  __syncthreads();

  const int w = tid >> 6, l = tid & 63, l15 = l & 15, q = l >> 4;
  const int m0 = blockIdx.x * 64 + w * 16;

  const int mA = m0 + l15;
  const int bA = mA >> 10, tA = mA & 1023;
  const unsigned short* a0 = h1 + ((size_t)tA * 64 + bA) * 256;
  const unsigned short* a1 = a0 + (size_t)1024 * 64 * 256;

  floatx4 acc[4];
#pragma unroll
  for (int nt = 0; nt < 4; ++nt) acc[nt] = (floatx4){0.f, 0.f, 0.f, 0.f};

#pragma unroll
  for (int ks = 0; ks < 8; ++ks) {
    short8 af = *(const short8*)(a0 + ks * 32 + q * 8);
#pragma unroll
    for (int nt = 0; nt < 4; ++nt) {
      short8 bf = *(const short8*)(sW + (nt * 16 + l15) * 512 + ks * 32 + q * 8);
      acc[nt] = MFMA_BF16(af, bf, acc[nt]);
    }
  }
#pragma unroll
  for (int ks = 0; ks < 8; ++ks) {
    short8 af = *(const short8*)(a1 + ks * 32 + q * 8);
#pragma unroll
    for (int nt = 0; nt < 4; ++nt) {
      short8 bf = *(const short8*)(sW + (nt * 16 + l15) * 512 + 256 + ks * 32 + q * 8);
      acc[nt] = MFMA_BF16(af, bf, acc[nt]);
    }
  }

#pragma unroll
  for (int nt = 0; nt < 4; ++nt) {
    const float bv = fcb[nt * 16 + l15];
#pragma unroll
    for (int r = 0; r < 4; ++r) {
      const int m = m0 + q * 4 + r;
      out[(size_t)m * 64 + nt * 16 + l15] = __expf(clamp_fc(acc[nt][r] + bv));
    }
  }
}

// ---------------------------------------------------------------------------
__global__ void diag_kernel(float* out, int n, float code) {
  int i = blockIdx.x * 256 + threadIdx.x;
  if (i < n) out[i] = (i == 0) ? code : 1.0f;
}

// ---------------------------------------------------------------------------

extern "C" void kernel_launch(void* const* d_in, const int* in_sizes, int n_in,
                              void* d_out, int out_size, void* d_ws, size_t ws_size,
                              hipStream_t stream) {
  const float* x       = (const float*)d_in[0];
  const float* Wih_l0f = (const float*)d_in[1];
  const float* Whh_l0f = (const float*)d_in[2];
  const float* b_l0f   = (const float*)d_in[3];
  const float* Wih_l0b = (const float*)d_in[4];
  const float* Whh_l0b = (const float*)d_in[5];
  const float* b_l0b   = (const float*)d_in[6];
  const float* Wih_l1f = (const float*)d_in[7];
  const float* Whh_l1f = (const float*)d_in[8];
  const float* b_l1f   = (const float*)d_in[9];
  const float* Wih_l1b = (const float*)d_in[10];
  const float* Whh_l1b = (const float*)d_in[11];
  const float* b_l1b   = (const float*)d_in[12];
  const float* fc_W    = (const float*)d_in[13];
  const float* fc_b    = (const float*)d_in[14];
  float* out = (float*)d_out;

  const size_t H_BYTES = (size_t)2 * 1024 * 64 * 256 * 2;  // 64MB

  if (ws_size < H_BYTES) {
    diag_kernel<<<dim3((out_size + 255) / 256), dim3(256), 0, stream>>>(
        out, out_size, 200.0f + (float)(ws_size >> 20));
    return;
  }

  unsigned short* h0 = (unsigned short*)d_ws;     // [2][T][B][256] bf16, 64MB
  unsigned short* h1 = (unsigned short*)d_in[0];  // x buf (fp32, 64MB): dead
                                                  // after layer-0 -> h1 bf16
  // d_out: [0,~2MB) flags: per layer {[2][1024][4][32] + 32-word done line}
  //        | [4MB,+2MB) wb1.
  unsigned int* flags = (unsigned int*)d_out;
  unsigned short* wb1 = (unsigned short*)((uint8_t*)d_out + (4u << 20));
  const size_t L_STRIDE = (size_t)2 * 1024 * 4 * 32 + 32;  // u32 words/layer

  hipMemsetAsync(flags, 0, (2u << 20) + 4096, stream);

  // Wih_l1{f,b} fp32 -> bf16 into d_out's dead region.
  cvt_kernel<<<dim3(512), dim3(256), 0, stream>>>(
      Wih_l1f, wb1, 1024 * 512, Wih_l1b, wb1 + (size_t)1024 * 512, 1024 * 512);

  lstm_layer_kernel<0><<<dim3(256), dim3(256), 0, stream>>>(
      x, nullptr, Wih_l0f, Wih_l0b, nullptr, Whh_l0f, Whh_l0b, b_l0f, b_l0b,
      h0, flags);
  lstm_layer_kernel<1><<<dim3(256), dim3(256), 0, stream>>>(
      nullptr, h0, nullptr, nullptr, wb1, Whh_l1f, Whh_l1b, b_l1f, b_l1b,
      h1, flags + L_STRIDE);
  fc_head_kernel<<<dim3(1024), dim3(256), 0, stream>>>(h1, fc_W, fc_b, out);
}

// Round 5
// 12870.688 us; speedup vs baseline: 1.4186x; 1.1071x over previous
//
#include <hip/hip_runtime.h>
#include <stdint.h>

// BiLSTM fused: B=64, T=1024, D=256, H=256/dir, O=64. In fp32, out fp32.
// History: R11 @14.1ms best (flag protocol, 4-5 fabric legs/step). R12
// sentinel regressed but was confounded (scatter polls, heavy per-round VALU,
// sleep, Wih churn). R13 fence regressed. R14 heaters proved clocks are NOT
// the term (VALUBusy 43%, dur unchanged) -> the ~7us/step is serialized
// fabric round-trips. R15 = minimum-leg protocol: ONE fabric crossing/step.
//   - Producer: fire-and-forget write-through 8B agent store of h (proven
//     transport). NO vmcnt ack, NO flag, nothing else.
//   - Consumer: polls the DATA (sentinel 0xFF = bf16 NaN, unreachable since
//     gates clamped => |h|<1): one round = 16 coalesced 8B agent loads over
//     its contiguous 8KB working set (R13 wave-exclusive layout), validity =
//     all dwords != 0xFFFFFFFF. The poll RETURNS the MFMA operands -> the
//     separate h-load leg disappears. Split in 2 halves so half-1 MFMAs
//     overlap half-2 poll; live poll buffer = 16 VGPRs.
//   - memset 0xFF pre-fill is safe: stream-ordered blit + kernel-boundary
//     writeback means no dirty 0xFF lines can later clobber produced data.
//   - Both layers stream Wih (bf16 pre-cvt, L2-resident) -> ~210 VGPRs, no
//     spill in the poll path (R11 proved streaming == resident in time).
//   - No heaters (R14: neutral), no s_sleep (hot spin), grid 32.
//
// Structure: 32 WGs per layer (2 dirs x 16 hidden-slices g); WG g owns hidden
// cols j in [16g,16g+16) == gate rows {j,256+j,512+j,768+j}.
//   acc[gate] = bias + Wih @ x[t]^T + Whh @ h[t-1]^T      (D[j][b], fp32 acc)
// Exchange layout per dir: [1024 t][4 w][16 g][16 b_l][16 j_l] bf16 — slot
// (t,w,g) is written by exactly one wave (512B, coalesced), and consumer
// wave (g*,w)'s step working set is slots (t,w,0..15) = 8KB contiguous.
//
// Memory plan: d_ws = h0 exch [2][1024][4][16][16][16] bf16 (64MB).
//   x buf (d_in[0], fp32, 64MB, dead after layer-0) -> h1 bf16 (exact fit),
//   0xFF-filled between the layer kernels (stream-ordered).
//   d_out (16MB): [0,2MB) wb1 = Wih_l1 bf16 | [2MB,3MB) wb0 = Wih_l0 bf16.
//   FC head runs last, overwrites all of d_out.

typedef __attribute__((ext_vector_type(8))) short short8;   // 8 x bf16
typedef __attribute__((ext_vector_type(4))) float floatx4;  // MFMA acc

#define MFMA_BF16(A, B, C) __builtin_amdgcn_mfma_f32_16x16x32_bf16(A, B, C, 0, 0, 0)

__device__ __forceinline__ unsigned short f2bf(float f) {
  unsigned u = __float_as_uint(f);
  u += 0x7FFFu + ((u >> 16) & 1u);  // RNE
  return (unsigned short)(u >> 16);
}
__device__ __forceinline__ short8 load_cvt8(const float* p) {
  short8 r;
#pragma unroll
  for (int i = 0; i < 8; ++i) r[i] = (short)f2bf(p[i]);
  return r;
}
// NaN-killing clamps; inert for legit values (|gate preact| <~ 5, fc <~ 0.6).
__device__ __forceinline__ float clamp_gate(float x) { return fminf(30.f, fmaxf(-30.f, x)); }
__device__ __forceinline__ float clamp_fc(float x) { return fminf(4.f, fmaxf(-30.f, x)); }
__device__ __forceinline__ float sigm(float x) { return 1.0f / (1.0f + __expf(-x)); }
__device__ __forceinline__ float tanh_fast(float x) { return 1.0f - 2.0f / (1.0f + __expf(2.0f * x)); }

// 8B word valid iff neither dword is all-ones (bf16 0xFFFF is NaN; f2bf of
// clamped |h|<1 never produces it). Per-dword check tolerates 4B tearing.
__device__ __forceinline__ bool wok(unsigned long long v) {
  return ((unsigned)v != 0xFFFFFFFFu) & ((unsigned)(v >> 32) != 0xFFFFFFFFu);
}

// ---------------------------------------------------------------------------
// fp32 -> bf16 conversion (two regions), grid-strided.
// ---------------------------------------------------------------------------
__global__ __launch_bounds__(256) void cvt_kernel(
    const float* __restrict__ s0, unsigned short* __restrict__ d0, int n0,
    const float* __restrict__ s1, unsigned short* __restrict__ d1, int n1) {
  const int stride = gridDim.x * 256;
  for (int j = blockIdx.x * 256 + threadIdx.x; j < n0; j += stride) d0[j] = f2bf(s0[j]);
  for (int j = blockIdx.x * 256 + threadIdx.x; j < n1; j += stride) d1[j] = f2bf(s1[j]);
}

// ---------------------------------------------------------------------------
// One bidirectional LSTM layer, fused input GEMM + recurrence.
// LAYER=0: input = x fp32 [B][T][256] (per-step cvt), K=256.
// LAYER=1: input = h0 exch layout bf16 (K=512 concat of both dirs).
// Both layers stream Wih bf16 from cache; Whh lives in VGPRs.
// ---------------------------------------------------------------------------
template <int LAYER>
__global__ __launch_bounds__(256, 1) void lstm_layer_kernel(
    const float* __restrict__ xf32,          // LAYER 0 input
    const unsigned short* __restrict__ xbf,  // LAYER 1 input (h0, exch layout)
    const unsigned short* __restrict__ wih,  // bf16 [2][1024][KDIM]
    const float* __restrict__ WhhF, const float* __restrict__ WhhB,
    const float* __restrict__ bF, const float* __restrict__ bB,
    unsigned short* __restrict__ hout) {     // exch layout [2][...]
  constexpr int NKS = LAYER ? 16 : 8;
  constexpr int KDIM = NKS * 32;
  constexpr size_t DIRSZ = (size_t)1024 * 16384;  // shorts per dir

  const int bx = blockIdx.x;
  const int dir = bx >> 4;
  const int g = bx & 15;
  const int tid = threadIdx.x;
  const int w = tid >> 6, l = tid & 63, l15 = l & 15, q = l >> 4;

  const float* Whh = dir ? WhhB : WhhF;
  const float* bias = dir ? bB : bF;

  // Whh A-fragments: cvt fp32 -> bf16 once (lane l15 -> j-row, q -> k-quad).
  short8 whh[4][8];
#pragma unroll
  for (int gi = 0; gi < 4; ++gi) {
    const float* wr = Whh + (size_t)(gi * 256 + g * 16 + l15) * 256;
#pragma unroll
    for (int ks = 0; ks < 8; ++ks) whh[gi][ks] = load_cvt8(wr + ks * 32 + q * 8);
  }

  const unsigned short* wd = wih + (size_t)dir * 1024 * KDIM;

  // Bias (fp32) for this lane's 16 outputs (gi, r) at j = g*16 + q*4 + r.
  float bvp[16];
#pragma unroll
  for (int gi = 0; gi < 4; ++gi)
#pragma unroll
    for (int r = 0; r < 4; ++r) bvp[gi * 4 + r] = bias[gi * 256 + g * 16 + q * 4 + r];

  const int b = w * 16 + l15;  // batch index this lane feeds (B-fragment)
  unsigned short* hd = hout + (size_t)dir * DIRSZ;

  float c[4] = {0.f, 0.f, 0.f, 0.f};

  for (int it = 0; it < 1024; ++it) {
    const int t = dir ? (1023 - it) : it;
    const int tp = dir ? (t + 1) : (t - 1);

    floatx4 acc[4];
#pragma unroll
    for (int gi = 0; gi < 4; ++gi)
#pragma unroll
      for (int r = 0; r < 4; ++r) acc[gi][r] = bvp[gi * 4 + r];

    // ---- x-part (independent of h[t-1]; overlaps peers' publish) ----
#pragma unroll
    for (int ks = 0; ks < NKS; ++ks) {
      short8 xf;
      if (LAYER == 0) {
        xf = load_cvt8(xf32 + (((size_t)b << 10) + t) * 256 + ks * 32 + q * 8);
      } else {
        const int k = ks * 32 + q * 8;
        const int gp = (k & 255) >> 4;  // = (ks&7)*2 + (q>>1)
        const size_t off = (size_t)(k >> 8) * DIRSZ +
                           (((size_t)t * 4 + w) * 16 + gp) * 256 + l15 * 16 +
                           (k & 15);
        xf = *(const short8*)(xbf + off);
      }
#pragma unroll
      for (int gi = 0; gi < 4; ++gi) {
        const short8 wfrag = *(const short8*)(
            wd + (size_t)(gi * 256 + g * 16 + l15) * KDIM + ks * 32 + q * 8);
        acc[gi] = MFMA_BF16(wfrag, xf, acc[gi]);
      }
    }

    // ---- recurrent part: poll the data itself (one fabric leg) ----
    if (it > 0) {
      const unsigned short* hbase = hd + ((size_t)tp * 4 + w) * (16 * 256);
      const int sub = l15 * 16 + (q & 1) * 8;  // shorts within a slot
#pragma unroll
      for (int half = 0; half < 2; ++half) {
        unsigned long long hwv[8];
        for (;;) {
          bool ok = true;
#pragma unroll
          for (int ks4 = 0; ks4 < 4; ++ks4) {
            const int ks = half * 4 + ks4;
            const unsigned long long* p = (const unsigned long long*)(
                hbase + (size_t)(ks * 2 + (q >> 1)) * 256 + sub);
            hwv[2 * ks4] =
                __hip_atomic_load(p, __ATOMIC_RELAXED, __HIP_MEMORY_SCOPE_AGENT);
            hwv[2 * ks4 + 1] =
                __hip_atomic_load(p + 1, __ATOMIC_RELAXED, __HIP_MEMORY_SCOPE_AGENT);
          }
#pragma unroll
          for (int i = 0; i < 8; ++i) ok = ok & wok(hwv[i]);
          if (__all(ok)) break;
        }
#pragma unroll
        for (int ks4 = 0; ks4 < 4; ++ks4) {
          short8 hf;
          ((unsigned long long*)&hf)[0] = hwv[2 * ks4];
          ((unsigned long long*)&hf)[1] = hwv[2 * ks4 + 1];
#pragma unroll
          for (int gi = 0; gi < 4; ++gi)
            acc[gi] = MFMA_BF16(whh[gi][half * 4 + ks4], hf, acc[gi]);
        }
      }
    }

    // ---- gates (i,f,g,o all in this lane) ----
    unsigned long long hv = 0ull;
#pragma unroll
    for (int r = 0; r < 4; ++r) {
      const float si = sigm(clamp_gate(acc[0][r]));
      const float sf = sigm(clamp_gate(acc[1][r]));
      const float tg = tanh_fast(clamp_gate(acc[2][r]));
      const float so = sigm(clamp_gate(acc[3][r]));
      const float cn = sf * c[r] + si * tg;
      c[r] = cn;
      const unsigned short hb16 = f2bf(so * tanh_fast(cn));
      hv |= ((unsigned long long)hb16) << (16 * r);
    }

    // ---- publish h: fire-and-forget write-through 8B store. That's all. ----
    // Slot (t,w,g) is wave-exclusive; word validity IS the signal.
    __hip_atomic_store(
        (unsigned long long*)(hd + (((size_t)t * 4 + w) * 16 + g) * 256 +
                              l15 * 16 + q * 4),
        hv, __ATOMIC_RELAXED, __HIP_MEMORY_SCOPE_AGENT);
  }
}

// ---------------------------------------------------------------------------
// FC head: out[b][t][o] = exp(h1concat[t][b][:] @ fc_W[o][:]^T + fc_b[o])
// h1 is in exch layout. fc_W fp32 -> bf16 into LDS once per block. Grid 1024
// x 256thr; block covers 64 rows (m = b*1024+t). OUTPUT FP32.
// ---------------------------------------------------------------------------
__global__ __launch_bounds__(256) void fc_head_kernel(
    const unsigned short* __restrict__ h1,  // exch layout [2][...] bf16
    const float* __restrict__ fcW,          // [64][512] fp32
    const float* __restrict__ fcb,          // [64] fp32
    float* __restrict__ out) {              // [B][T][64] fp32
  constexpr size_t DIRSZ = (size_t)1024 * 16384;
  __shared__ unsigned short sW[64 * 512];
  const int tid = threadIdx.x;
  for (int i = tid; i < 64 * 512; i += 256) sW[i] = f2bf(fcW[i]);
  __syncthreads();

  const int w = tid >> 6, l = tid & 63, l15 = l & 15, q = l >> 4;
  const int m0 = blockIdx.x * 64 + w * 16;

  const int mA = m0 + l15;
  const int bA = mA >> 10, tA = mA & 1023;
  // Lane's A-row base within a dir: [tA][w'=bA>>4][g'][b_l=bA&15][j_l].
  const size_t arow = ((size_t)tA * 4 + (bA >> 4)) * (16 * 256) +
                      (size_t)(bA & 15) * 16 + (q & 1) * 8;

  floatx4 acc[4];
#pragma unroll
  for (int nt = 0; nt < 4; ++nt) acc[nt] = (floatx4){0.f, 0.f, 0.f, 0.f};

#pragma unroll
  for (int dh = 0; dh < 2; ++dh) {
    const unsigned short* ad = h1 + (size_t)dh * DIRSZ;
#pragma unroll
    for (int ks = 0; ks < 8; ++ks) {
      const int gp = ks * 2 + (q >> 1);
      short8 af = *(const short8*)(ad + arow + (size_t)gp * 256);
#pragma unroll
      for (int nt = 0; nt < 4; ++nt) {
        short8 bf = *(const short8*)(sW + (nt * 16 + l15) * 512 + dh * 256 +
                                     ks * 32 + q * 8);
        acc[nt] = MFMA_BF16(af, bf, acc[nt]);
      }
    }
  }

#pragma unroll
  for (int nt = 0; nt < 4; ++nt) {
    const float bv = fcb[nt * 16 + l15];
#pragma unroll
    for (int r = 0; r < 4; ++r) {
      const int m = m0 + q * 4 + r;
      out[(size_t)m * 64 + nt * 16 + l15] = __expf(clamp_fc(acc[nt][r] + bv));
    }
  }
}

// ---------------------------------------------------------------------------
__global__ void diag_kernel(float* out, int n, float code) {
  int i = blockIdx.x * 256 + threadIdx.x;
  if (i < n) out[i] = (i == 0) ? code : 1.0f;
}

// ---------------------------------------------------------------------------

extern "C" void kernel_launch(void* const* d_in, const int* in_sizes, int n_in,
                              void* d_out, int out_size, void* d_ws, size_t ws_size,
                              hipStream_t stream) {
  const float* x       = (const float*)d_in[0];
  const float* Wih_l0f = (const float*)d_in[1];
  const float* Whh_l0f = (const float*)d_in[2];
  const float* b_l0f   = (const float*)d_in[3];
  const float* Wih_l0b = (const float*)d_in[4];
  const float* Whh_l0b = (const float*)d_in[5];
  const float* b_l0b   = (const float*)d_in[6];
  const float* Wih_l1f = (const float*)d_in[7];
  const float* Whh_l1f = (const float*)d_in[8];
  const float* b_l1f   = (const float*)d_in[9];
  const float* Wih_l1b = (const float*)d_in[10];
  const float* Whh_l1b = (const float*)d_in[11];
  const float* b_l1b   = (const float*)d_in[12];
  const float* fc_W    = (const float*)d_in[13];
  const float* fc_b    = (const float*)d_in[14];
  float* out = (float*)d_out;

  const size_t H_BYTES = (size_t)2 * 1024 * 64 * 256 * 2;  // 64MB

  if (ws_size < H_BYTES) {
    diag_kernel<<<dim3((out_size + 255) / 256), dim3(256), 0, stream>>>(
        out, out_size, 200.0f + (float)(ws_size >> 20));
    return;
  }

  unsigned short* h0 = (unsigned short*)d_ws;     // exch layout, 64MB
  unsigned short* h1 = (unsigned short*)d_in[0];  // x buf (fp32, 64MB): dead
                                                  // after layer-0 -> h1 bf16
  // d_out: [0,2MB) wb1 = Wih_l1 bf16 | [2MB,3MB) wb0 = Wih_l0 bf16.
  unsigned short* wb1 = (unsigned short*)d_out;
  unsigned short* wb0 = (unsigned short*)((uint8_t*)d_out + (2u << 20));

  // Sentinel-fill h0 (h1 is filled after layer-0 frees the x buffer).
  hipMemsetAsync(h0, 0xFF, H_BYTES, stream);

  // Wih fp32 -> bf16 into d_out's dead prefix.
  cvt_kernel<<<dim3(512), dim3(256), 0, stream>>>(
      Wih_l1f, wb1, 1024 * 512, Wih_l1b, wb1 + (size_t)1024 * 512, 1024 * 512);
  cvt_kernel<<<dim3(512), dim3(256), 0, stream>>>(
      Wih_l0f, wb0, 1024 * 256, Wih_l0b, wb0 + (size_t)1024 * 256, 1024 * 256);

  lstm_layer_kernel<0><<<dim3(32), dim3(256), 0, stream>>>(
      x, nullptr, wb0, Whh_l0f, Whh_l0b, b_l0f, b_l0b, h0);
  hipMemsetAsync(h1, 0xFF, H_BYTES, stream);  // stream-ordered after layer-0
  lstm_layer_kernel<1><<<dim3(32), dim3(256), 0, stream>>>(
      nullptr, h0, wb1, Whh_l1f, Whh_l1b, b_l1f, b_l1b, h1);
  fc_head_kernel<<<dim3(1024), dim3(256), 0, stream>>>(h1, fc_W, fc_b, out);
}